// Round 3
// baseline (522.785 us; speedup 1.0000x reference)
//
#include <hip/hip_runtime.h>

typedef short bf16x8 __attribute__((ext_vector_type(8)));
typedef float f32x4 __attribute__((ext_vector_type(4)));

__device__ __forceinline__ unsigned short f2bf(float f) {
  unsigned x = __float_as_uint(f);
  return (unsigned short)((x + 0x7fffu + ((x >> 16) & 1u)) >> 16);  // RNE
}

// ---------------------------------------------------------------------------
// Tile images: 18432 B = 9216 u16 = 128 rows x 64 k.
//   A-tiles (X, H):  elem (r, k) at  r*72 + k                      (pad 64->72)
//   W-tiles:         elem (n, k) at  n*72 + (k ^ (((n>>3)&7)<<3))  (pad + XOR)
// Exact LDS layout the GEMM uses -> GEMM staging is a verbatim linear copy.
//
// Split-K partials: slice z holds per-tile 64 KB slots in MFMA-native order
//   s = lane + 64*r + 256*ni + 1024*mi + 4096*wave   (slot = mt*PX + p)
// so every GEMM epilogue store is a 256 B wave-contiguous full-line write.
// ---------------------------------------------------------------------------

// x [256][4096] f32 -> Ximg tiles [mt<2][kt<64]
__global__ __launch_bounds__(256)
void pack_x(const float* __restrict__ x, unsigned short* __restrict__ img) {
  const int i = (blockIdx.x * 256 + threadIdx.x) * 8;   // 1M elems, 512 blocks
  const int m = i >> 12, k = i & 4095;
  float q[8];
  *(float4*)(q)     = *(const float4*)(x + i);
  *(float4*)(q + 4) = *(const float4*)(x + i + 4);
  union { unsigned short u[8]; int4 v; } t;
#pragma unroll
  for (int j = 0; j < 8; ++j) t.u[j] = f2bf(q[j]);
  const size_t o = (size_t)((m >> 7) * 64 + (k >> 6)) * 9216 + (m & 127) * 72 + (k & 63);
  *(int4*)(img + o) = t.v;
}

// W1 [4096][8192] f32 -> panel p (128 cols), live tiles kt<=p. LDS-free:
// thread owns (n, k-octet): 8 lane-coalesced scalar loads -> one int4 store.
__global__ __launch_bounds__(256)
void pack_w1(const float* __restrict__ W, unsigned short* __restrict__ img) {
  const int p = blockIdx.x;          // 0..63
  const int kt = blockIdx.y;         // 0..63
  if (kt > p) return;                // live k < (p+1)*64
  const int t = threadIdx.x;
  const int n = t & 127, kh = t >> 7;
  const float* src = W + (size_t)(kt * 64) * 8192 + p * 128 + n;
  unsigned short* dst = img + (size_t)(p * (p + 1) / 2 + kt) * 9216 + n * 72;
  const int xr = ((n >> 3) & 7) << 3;
#pragma unroll
  for (int g = 0; g < 4; ++g) {
    const int kb = (kh * 4 + g) * 8;
    union { unsigned short u[8]; int4 v; } tt;
#pragma unroll
    for (int j = 0; j < 8; ++j)
      tt.u[j] = f2bf(src[(size_t)(kb + j) * 8192]);
    *(int4*)(dst + (kb ^ xr)) = tt.v;
  }
}

// W2 [8192][4096] f32 -> panel p (128 cols = mask col-blocks {2p,2p+1}),
// live tiles kt < 4p+4; cols with col-block cb live for k < (cb+1)*128.
__global__ __launch_bounds__(256)
void pack_w2(const float* __restrict__ W, unsigned short* __restrict__ img) {
  const int p = blockIdx.x;          // 0..31
  const int kt = blockIdx.y;         // 0..127
  if (kt >= 4 * p + 4) return;
  const int t = threadIdx.x;
  const int n = t & 127, kh = t >> 7;
  const int lk = (2 * p + 1 + (n >= 64 ? 1 : 0)) * 128;  // live k limit
  const float* src = W + (size_t)(kt * 64) * 4096 + p * 128 + n;
  unsigned short* dst = img + (size_t)(2 * p * (p + 1) + kt) * 9216 + n * 72;
  const int xr = ((n >> 3) & 7) << 3;
#pragma unroll
  for (int g = 0; g < 4; ++g) {
    const int kb = (kh * 4 + g) * 8;
    union { unsigned short u[8]; int4 v; } tt;
#pragma unroll
    for (int j = 0; j < 8; ++j) {
      const int k = kt * 64 + kb + j;
      tt.u[j] = (k < lk) ? f2bf(src[(size_t)(kb + j) * 4096]) : (unsigned short)0;
    }
    *(int4*)(dst + (kb ^ xr)) = tt.v;
  }
}

// Himg = packed bf16 tiles of relu(sum_z P1 + b1); inverts the MFMA layout.
__global__ __launch_bounds__(256)
void reduce1(const float* __restrict__ P, const float* __restrict__ b1,
             unsigned short* __restrict__ img) {
  const int s = (blockIdx.x * 256 + threadIdx.x) * 4;   // 2048 blocks
  f32x4 a = *(const f32x4*)(P + s);
#pragma unroll
  for (int z = 1; z < 4; ++z)
    a += *(const f32x4*)(P + (size_t)z * 2097152 + s);
  const int lane = s & 63, r = (s >> 6) & 3, ni = (s >> 8) & 3;
  const int mi = (s >> 10) & 3, wv = (s >> 12) & 3, slot = s >> 14;
  const int p = slot & 63, mt = slot >> 6;
  const int m = mt * 128 + (wv & 1) * 64 + mi * 16 + (lane >> 4) * 4 + r;
  const int n = p * 128 + (wv >> 1) * 64 + ni * 16 + (lane & 15);
  a += *(const f32x4*)(b1 + n);
  union { unsigned short u[4]; int2 v; } t;
#pragma unroll
  for (int j = 0; j < 4; ++j) t.u[j] = f2bf(fmaxf(a[j], 0.f));
  const size_t o = (size_t)((m >> 7) * 128 + (n >> 6)) * 9216 + (m & 127) * 72 + (n & 63);
  *(int2*)(img + o) = t.v;
}

// out = sum_z P2 + b2; inverts the MFMA layout.
__global__ __launch_bounds__(256)
void reduce2(const float* __restrict__ P, const float* __restrict__ b2,
             float* __restrict__ out) {
  const int s = (blockIdx.x * 256 + threadIdx.x) * 4;   // 1024 blocks
  f32x4 a = *(const f32x4*)(P + s);
#pragma unroll
  for (int z = 1; z < 8; ++z)
    a += *(const f32x4*)(P + (size_t)z * 1048576 + s);
  const int lane = s & 63, r = (s >> 6) & 3, ni = (s >> 8) & 3;
  const int mi = (s >> 10) & 3, wv = (s >> 12) & 3, slot = s >> 14;
  const int p = slot & 31, mt = slot >> 5;
  const int m = mt * 128 + (wv & 1) * 64 + mi * 16 + (lane >> 4) * 4 + r;
  const int n = p * 128 + (wv >> 1) * 64 + ni * 16 + (lane & 15);
  a += *(const f32x4*)(b2 + n);
  *(f32x4*)(out + (size_t)m * 4096 + n) = a;
}

// ---------------------------------------------------------------------------
// GEMM on packed images. BM=128, BN=128, BK=64; 256 thr = 4 waves (2x2), each
// wave owns a 64x64 quadrant (acc 4x4 frags). Staging = linear copy of two
// 18 KB tiles, prefetched one iter ahead. Panel p: nIter = p*IM + IA live
// BK-tiles, W tile base = IM*p(p-1)/2 + IA*p. Split-K over KS z; each z
// writes a private 64 KB permuted slot (full-line streaming stores).
// Empty z-ranges zero-fill their slot. Heavy (high-p) tiles dispatch first.
// ---------------------------------------------------------------------------
template<int IM, int IA, int KT, int KS>
__global__ __launch_bounds__(256, 3)
void gemm_img(const unsigned short* __restrict__ Aimg,
              const unsigned short* __restrict__ Wimg,
              float* __restrict__ part) {
  __shared__ unsigned short Xs[9216];   // A-tile image
  __shared__ unsigned short Ws[9216];   // W-tile image

  const int PX = (int)gridDim.x;
  const int p  = PX - 1 - (int)blockIdx.x;
  const int mt = blockIdx.y;
  const int nIter = p * IM + IA;
  const int i0 = (int)blockIdx.z * nIter / KS;
  const int i1 = ((int)blockIdx.z + 1) * nIter / KS;

  float* po = part + (size_t)blockIdx.z * ((size_t)PX * 2 * 16384)
                   + (size_t)(mt * PX + p) * 16384;
  const int tid = threadIdx.x;

  if (i0 == i1) {                       // empty range: zero-fill slot, leave
    const f32x4 z4 = (f32x4){0.f, 0.f, 0.f, 0.f};
#pragma unroll
    for (int j = 0; j < 16; ++j)
      *(f32x4*)(po + (tid + j * 256) * 4) = z4;
    return;
  }

  const size_t tb = (size_t)IM * ((size_t)p * (p - 1) / 2) + (size_t)IA * p;
  const char* Wp = (const char*)Wimg + tb * 18432;
  const char* Ap = (const char*)Aimg + (size_t)mt * KT * 18432;

  const int lane = tid & 63, wave = tid >> 6;
  const int l15 = lane & 15, quad = lane >> 4;
  const int wm0 = (wave & 1) * 64, wn0 = (wave >> 1) * 64;

  // staging: per-wave 9 KB linear chunk (waves 0,1 -> Xs; 2,3 -> Ws)
  const char* gsrc0 = (wave < 2) ? Ap : Wp;
  const int   half  = (wave & 1) * 9216;
  char*       ldst  = ((wave < 2) ? (char*)Xs : (char*)Ws) + half;
  const int   loff  = lane * 16;

  int4 st[9];
  auto loadG = [&](int kt) {
    const char* g = gsrc0 + (size_t)kt * 18432 + half + loff;
#pragma unroll
    for (int j = 0; j < 9; ++j) st[j] = *(const int4*)(g + j * 1024);
  };
  auto storeL = [&]() {
#pragma unroll
    for (int j = 0; j < 9; ++j) *(int4*)(ldst + loff + j * 1024) = st[j];
  };

  f32x4 acc[4][4];
#pragma unroll
  for (int mi = 0; mi < 4; ++mi)
#pragma unroll
    for (int ni = 0; ni < 4; ++ni)
      acc[mi][ni] = (f32x4){0.f, 0.f, 0.f, 0.f};

  loadG(i0);
  for (int kt = i0; kt < i1; ++kt) {
    __syncthreads();                    // prior tile's LDS reads done
    storeL();
    if (kt + 1 < i1) loadG(kt + 1);     // prefetch overlaps barrier+MFMA
    __syncthreads();                    // stores visible
#pragma unroll
    for (int kk = 0; kk < 64; kk += 32) {
      bf16x8 af[4], bfr[4];
#pragma unroll
      for (int mi = 0; mi < 4; ++mi)
        af[mi] = *(const bf16x8*)(&Xs[(wm0 + mi * 16 + l15) * 72 + kk + quad * 8]);
#pragma unroll
      for (int ni = 0; ni < 4; ++ni) {
        const int n = wn0 + ni * 16 + l15;
        bfr[ni] = *(const bf16x8*)(&Ws[n * 72 + ((kk + quad * 8) ^ (((n >> 3) & 7) << 3))]);
      }
#pragma unroll
      for (int mi = 0; mi < 4; ++mi)
#pragma unroll
        for (int ni = 0; ni < 4; ++ni)
          acc[mi][ni] = __builtin_amdgcn_mfma_f32_16x16x32_bf16(
              af[mi], bfr[ni], acc[mi][ni], 0, 0, 0);
    }
  }

  // epilogue: permuted full-line streaming stores (256 B per wave-instr)
  float* ps = po + wave * 4096 + lane;
#pragma unroll
  for (int mi = 0; mi < 4; ++mi)
#pragma unroll
    for (int ni = 0; ni < 4; ++ni)
#pragma unroll
      for (int r = 0; r < 4; ++r)
        ps[mi * 1024 + ni * 256 + r * 64] = acc[mi][ni][r];
}

extern "C" void kernel_launch(void* const* d_in, const int* in_sizes, int n_in,
                              void* d_out, int out_size, void* d_ws, size_t ws_size,
                              hipStream_t stream) {
  const float* x  = (const float*)d_in[0];  // [256,64,64] fp32
  const float* W1 = (const float*)d_in[1];  // [4096,8192] fp32
  const float* b1 = (const float*)d_in[2];  // [8192] fp32
  const float* W2 = (const float*)d_in[3];  // [8192,4096] fp32
  const float* b2 = (const float*)d_in[4];  // [4096] fp32
  // dims hardcoded: B=256, S=64, I=64, H=128, O=64

  // workspace layout (~119 MB), 256B-aligned; P region shared by P1/P2
  char* ws = (char*)d_ws;
  unsigned short* Ximg  = (unsigned short*)ws;                      //  2,359,296 B
  unsigned short* W1img = (unsigned short*)(ws + 2359296);          // 38,338,560 B
  unsigned short* Himg  = (unsigned short*)(ws + 40697856);         //  4,718,592 B
  unsigned short* W2img = (unsigned short*)(ws + 45416448);         // 38,928,384 B
  float*          P     = (float*)(ws + 84344832);                  // 33,554,432 B
  float* out = (float*)d_out;               // [256,4096] fp32

  pack_x <<<dim3(512),     256, 0, stream>>>(x,  Ximg);
  pack_w1<<<dim3(64, 64),  256, 0, stream>>>(W1, W1img);
  pack_w2<<<dim3(32, 128), 256, 0, stream>>>(W2, W2img);

  // GEMM1: Ximg @ W1img -> P1 [4][128 slots][16K].  nIter = p+1, KS=4.
  gemm_img<1, 1, 64, 4><<<dim3(64, 2, 4), 256, 0, stream>>>(Ximg, W1img, P);

  // Himg = bf16 tiles of relu(sum_z P1 + b1)
  reduce1<<<dim3(2048), 256, 0, stream>>>(P, b1, Himg);

  // GEMM2: Himg @ W2img -> P2 [8][64 slots][16K].  nIter = 4p+4, KS=8.
  gemm_img<4, 4, 128, 8><<<dim3(32, 2, 8), 256, 0, stream>>>(Himg, W2img, P);

  // out = sum_z P2 + b2
  reduce2<<<dim3(1024), 256, 0, stream>>>(P, b2, out);
}

// Round 4
// 338.514 us; speedup vs baseline: 1.5443x; 1.5443x over previous
//
#include <hip/hip_runtime.h>

typedef short bf16x8 __attribute__((ext_vector_type(8)));
typedef float f32x4 __attribute__((ext_vector_type(4)));

__device__ __forceinline__ unsigned short f2bf(float f) {
  unsigned x = __float_as_uint(f);
  return (unsigned short)((x + 0x7fffu + ((x >> 16) & 1u)) >> 16);  // RNE
}

// ---------------------------------------------------------------------------
// A-images (X, H): bf16 k-tiles of 64 k, elem (m, k) at
//     tile*16384 + m*64 + ((k&63) ^ ((m&7)<<3))        (32 KB per tile)
// MFMA A-fragments are contiguous 16 B at this layout -> per-lane global
// loads, no LDS for A. W streams raw fp32 -> bf16 LDS tile per BK-iter.
//
// Split-K partials: chunk slots of 64 KB in MFMA-native permuted order
//     s = lane + 64*r + 256*ni + 1024*mi + 4096*wave
// -> every epilogue store is a 256 B wave-contiguous full-line write.
// Chunk = 8 BK-iters. Per-panel chunk counts and closed-form bases:
//   gemm1: nt(p) = (p>>1)+1  (p<128), nc = ceil(nt/8),  base = chunkbase1(p)
//   gemm2: nt(p) = 2(p+1)    (p<64),  nc = ceil(nt/8),  base = chunkbase2(p)
// ---------------------------------------------------------------------------

__device__ __forceinline__ int chunkbase1(int p) {
  const int a = p >> 1, b = p & 1;
  const int al = a >> 3, be = a & 7;
  const int C8 = 4 * al * (al + 1) + be * (al + 1);   // sum_{q=1..a} ceil(q/8)
  return 2 * C8 + b * ((a + 8) >> 3);
}
__device__ __forceinline__ int chunkbase2(int p) {
  const int al = p >> 2, be = p & 3;                  // sum_{q=1..p} ceil(q/4)
  return 2 * al * (al + 1) + be * (al + 1);
}

// x [256][4096] f32 -> Ximg (64 k-tiles)
__global__ __launch_bounds__(256)
void pack_x(const float* __restrict__ x, unsigned short* __restrict__ img) {
  const int i = (blockIdx.x * 256 + threadIdx.x) * 8;   // 1M elems, 512 blocks
  const int m = i >> 12, k = i & 4095;
  float q[8];
  *(float4*)(q)     = *(const float4*)(x + i);
  *(float4*)(q + 4) = *(const float4*)(x + i + 4);
  union { unsigned short u[8]; int4 v; } t;
#pragma unroll
  for (int j = 0; j < 8; ++j) t.u[j] = f2bf(q[j]);
  const size_t o = (size_t)(k >> 6) * 16384 + m * 64 + ((k & 63) ^ ((m & 7) << 3));
  *(int4*)(img + o) = t.v;
}

// ---------------------------------------------------------------------------
// GEMM: block = (panel p: 64 N-cols, chunk c: up to 8 BK=64 iters), BM=256.
// 256 thr = 4 waves, wave w owns m in [w*64, w*64+64), acc 4x4 frags.
// W tile 64k x 64n staged fp32->bf16 into Ws[n*72 + (k ^ ((n>>3 &7)<<3))].
// A-frags loaded directly from Aimg (L2-resident), double-buffered in regs.
// nt = ((p>>PSH)+1)<<KSH ; MODE selects chunk base. Heavy panels first.
// ---------------------------------------------------------------------------
template<int PSH, int KSH, int MODE>
__global__ __launch_bounds__(256, 2)
void gemm_sk(const unsigned short* __restrict__ Aimg,
             const float* __restrict__ W,
             float* __restrict__ part, int N) {
  __shared__ unsigned short Ws[64 * 72];

  const int p = (int)gridDim.x - 1 - (int)blockIdx.x;
  const int c = blockIdx.y;
  const int nt = ((p >> PSH) + 1) << KSH;
  const int i0 = c * 8;
  if (i0 >= nt) return;                       // uniform exit, no barriers yet
  const int i1 = (i0 + 8 < nt) ? i0 + 8 : nt;
  const int base = (MODE == 1) ? chunkbase1(p) : chunkbase2(p);
  float* po = part + (size_t)(base + c) * 16384;

  const int tid = threadIdx.x, lane = tid & 63, wave = tid >> 6;
  const int l15 = lane & 15, quad = lane >> 4;

  // W staging: thread owns (rows rg+16j, cols l16*4..+3)
  const int l16 = tid & 15, rg = tid >> 4;
  const float* wbase = W + (size_t)p * 64 + l16 * 4;

  // A-fragment offsets within a k-tile
  int aoff[4][2];
#pragma unroll
  for (int mi = 0; mi < 4; ++mi) {
    const int m = wave * 64 + mi * 16 + l15;
#pragma unroll
    for (int h = 0; h < 2; ++h) {
      const int k8 = h * 32 + quad * 8;
      aoff[mi][h] = m * 64 + (k8 ^ ((m & 7) << 3));
    }
  }

  float4 wr[4];
  bf16x8 afA[4][2], afB[4][2];

  auto loadW = [&](int kt) {
#pragma unroll
    for (int j = 0; j < 4; ++j)
      wr[j] = *(const float4*)(wbase + (size_t)(kt * 64 + rg + j * 16) * N);
  };
  auto loadA = [&](bf16x8 (&af)[4][2], int kt) {
    const unsigned short* at = Aimg + (size_t)kt * 16384;
#pragma unroll
    for (int mi = 0; mi < 4; ++mi)
#pragma unroll
      for (int h = 0; h < 2; ++h)
        af[mi][h] = *(const bf16x8*)(at + aoff[mi][h]);
  };
  auto storeW = [&]() {
#pragma unroll
    for (int j = 0; j < 4; ++j) {
      const int r = rg + j * 16;
      const float* f = (const float*)&wr[j];
#pragma unroll
      for (int i = 0; i < 4; ++i) {
        const int cc = l16 * 4 + i;
        Ws[cc * 72 + (r ^ (((cc >> 3) & 7) << 3))] = f2bf(f[i]);
      }
    }
  };

  f32x4 acc[4][4];
#pragma unroll
  for (int mi = 0; mi < 4; ++mi)
#pragma unroll
    for (int ni = 0; ni < 4; ++ni)
      acc[mi][ni] = (f32x4){0.f, 0.f, 0.f, 0.f};

  auto STEP = [&](bf16x8 (&cur)[4][2], bf16x8 (&nxt)[4][2], int it) {
    __syncthreads();                          // prior iter's Ws reads done
    storeW();                                 // wr -> LDS (vmcnt auto)
    if (it + 1 < i1) { loadW(it + 1); loadA(nxt, it + 1); }  // prefetch
    __syncthreads();                          // Ws visible
#pragma unroll
    for (int h = 0; h < 2; ++h) {
      const int kk = h * 32;
      bf16x8 bfr[4];
#pragma unroll
      for (int ni = 0; ni < 4; ++ni) {
        const int n = ni * 16 + l15;
        bfr[ni] = *(const bf16x8*)(
            &Ws[n * 72 + ((kk + quad * 8) ^ (((n >> 3) & 7) << 3))]);
      }
#pragma unroll
      for (int mi = 0; mi < 4; ++mi)
#pragma unroll
        for (int ni = 0; ni < 4; ++ni)
          acc[mi][ni] = __builtin_amdgcn_mfma_f32_16x16x32_bf16(
              cur[mi][h], bfr[ni], acc[mi][ni], 0, 0, 0);
    }
  };

  loadW(i0);
  loadA(afA, i0);
  int it = i0;
  while (true) {
    STEP(afA, afB, it); if (++it >= i1) break;
    STEP(afB, afA, it); if (++it >= i1) break;
  }

  // epilogue: permuted full-line streaming stores (256 B per wave-instr)
  float* ps = po + wave * 4096 + lane;
#pragma unroll
  for (int mi = 0; mi < 4; ++mi)
#pragma unroll
    for (int ni = 0; ni < 4; ++ni)
#pragma unroll
      for (int r = 0; r < 4; ++r)
        ps[mi * 1024 + ni * 256 + r * 64] = acc[mi][ni][r];
}

// Himg = bf16 A-image tiles of relu(sum_c P1 + b1); inverts permuted layout.
__global__ __launch_bounds__(256)
void reduce1(const float* __restrict__ P, const float* __restrict__ b1,
             unsigned short* __restrict__ img) {
  const int g = blockIdx.x * 256 + threadIdx.x;  // 2048 blocks
  const int p = g >> 12;                         // H col-panel 0..127
  const int s = (g & 4095) * 4;
  const int nc = ((p >> 1) + 8) >> 3;
  const float* ps = P + (size_t)chunkbase1(p) * 16384 + s;
  f32x4 a = *(const f32x4*)ps;
  for (int ci = 1; ci < nc; ++ci)
    a += *(const f32x4*)(ps + (size_t)ci * 16384);
  const int lane = s & 63, r = (s >> 6) & 3, ni = (s >> 8) & 3;
  const int mi = (s >> 10) & 3, wv = (s >> 12) & 3;
  const int m  = wv * 64 + mi * 16 + (lane >> 4) * 4 + r;
  const int nl = ni * 16 + (lane & 15);
  a += *(const f32x4*)(b1 + p * 64 + nl);
  union { unsigned short u[4]; int2 v; } t;
#pragma unroll
  for (int j = 0; j < 4; ++j) t.u[j] = f2bf(fmaxf(a[j], 0.f));
  *(int2*)(img + (size_t)p * 16384 + m * 64 + (nl ^ ((m & 7) << 3))) = t.v;
}

// out = sum_c P2 + b2; inverts permuted layout, coalesced f32x4 stores.
__global__ __launch_bounds__(256)
void reduce2(const float* __restrict__ P, const float* __restrict__ b2,
             float* __restrict__ out) {
  const int g = blockIdx.x * 256 + threadIdx.x;  // 1024 blocks
  const int p = g >> 12;                         // out col-panel 0..63
  const int s = (g & 4095) * 4;
  const int nc = (p + 4) >> 2;
  const float* ps = P + (size_t)chunkbase2(p) * 16384 + s;
  f32x4 a = *(const f32x4*)ps;
  for (int ci = 1; ci < nc; ++ci)
    a += *(const f32x4*)(ps + (size_t)ci * 16384);
  const int lane = s & 63, r = (s >> 6) & 3, ni = (s >> 8) & 3;
  const int mi = (s >> 10) & 3, wv = (s >> 12) & 3;
  const int m  = wv * 64 + mi * 16 + (lane >> 4) * 4 + r;
  const int nl = ni * 16 + (lane & 15);
  a += *(const f32x4*)(b2 + p * 64 + nl);
  *(f32x4*)(out + (size_t)m * 4096 + p * 64 + nl) = a;
}

extern "C" void kernel_launch(void* const* d_in, const int* in_sizes, int n_in,
                              void* d_out, int out_size, void* d_ws, size_t ws_size,
                              hipStream_t stream) {
  const float* x  = (const float*)d_in[0];  // [256,64,64] fp32
  const float* W1 = (const float*)d_in[1];  // [4096,8192] fp32
  const float* b1 = (const float*)d_in[2];  // [8192] fp32
  const float* W2 = (const float*)d_in[3];  // [8192,4096] fp32
  const float* b2 = (const float*)d_in[4];  // [4096] fp32
  // dims hardcoded: B=256, S=64, I=64, H=128, O=64

  // workspace (~44 MB): Ximg 2 MB | Himg 4 MB | P 36.9 MB (shared P1/P2)
  char* ws = (char*)d_ws;
  unsigned short* Ximg = (unsigned short*)ws;                 //  2,097,152 B
  unsigned short* Himg = (unsigned short*)(ws + 2097152);     //  4,194,304 B
  float*          P    = (float*)(ws + 6291456);              // 37,748,736 B
  float* out = (float*)d_out;                                 // [256,4096] f32

  pack_x<<<dim3(512), 256, 0, stream>>>(x, Ximg);

  // GEMM1: Ximg @ W1 -> P1 (576 chunk slots).  nt = (p>>1)+1, panels 128.
  gemm_sk<1, 0, 1><<<dim3(128, 8), 256, 0, stream>>>(Ximg, W1, P, 8192);

  // Himg = bf16 image of relu(sum P1 + b1)
  reduce1<<<dim3(2048), 256, 0, stream>>>(P, b1, Himg);

  // GEMM2: Himg @ W2 -> P2 (544 chunk slots).  nt = 2(p+1), panels 64.
  gemm_sk<0, 1, 2><<<dim3(64, 16), 256, 0, stream>>>(Himg, W2, P, 4096);

  // out = sum P2 + b2
  reduce2<<<dim3(1024), 256, 0, stream>>>(P, b2, out);
}